// Round 1
// baseline (164.220 us; speedup 1.0000x reference)
//
#include <hip/hip_runtime.h>

#define T_LEN   2000
#define NTAP    12      // max real taps is 11; pad to 12 with w=0,off=0
#define KPB     32      // kernels per block
#define NKER    256
#define THREADS 256

// ---------------------------------------------------------------------------
// Prep: compress densified dilated kernel bank (NKER x Lmax, mostly zeros)
// into fixed-width tap lists: tw[k][j] (weight), toff[k][j] (offset in [0,Lmax)).
// Padded taps get w=0, off=0 (contribute nothing; read a valid LDS address).
// ---------------------------------------------------------------------------
__global__ void rocket_prep(const float* __restrict__ W, int Lmax,
                            float* __restrict__ tw, int* __restrict__ toff) {
    int k = blockIdx.x * blockDim.x + threadIdx.x;
    if (k >= NKER) return;
    int n = 0;
    for (int l = 0; l < Lmax; ++l) {
        float v = W[k * Lmax + l];
        if (v != 0.0f && n < NTAP) {
            tw[k * NTAP + n]   = v;
            toff[k * NTAP + n] = l;
            ++n;
        }
    }
    for (; n < NTAP; ++n) {
        tw[k * NTAP + n]   = 0.0f;
        toff[k * NTAP + n] = 0;
    }
}

// ---------------------------------------------------------------------------
// Main: one block per (bc, kernel-group). Stage padded x row in LDS.
// Each thread covers t = tid + i*256 (i=0..7); per kernel k: 12-tap FMA chain,
// running count-of-positives and max, then wave shuffle-reduce + cross-wave
// LDS combine. y[t] = bias + sum_j W[k,l_j] * x[t + l_j - (Lmax-1)/2]
// (cross-correlation, SAME padding) => with sx[p] = x[p - c0] zero-padded,
// y = bias + sum_j w_j * sx[t + off_j].
// ---------------------------------------------------------------------------
__global__ __launch_bounds__(THREADS) void rocket_main(
    const float* __restrict__ x, const float* __restrict__ bias,
    const float* __restrict__ tw, const int* __restrict__ toff,
    float* __restrict__ out, int Lmax) {

    __shared__ float sx[T_LEN + 128];     // padded row: T + Lmax - 1 <= 2126
    __shared__ float spart[4][KPB][2];    // per-wave partials (cnt, max)

    const int bc  = blockIdx.x;           // 0..255  (= b*32 + c)
    const int kg  = blockIdx.y;           // 0..7
    const int tid = threadIdx.x;
    const int c0  = (Lmax - 1) >> 1;
    const int ext = T_LEN + Lmax - 1;

    const float* __restrict__ xr = x + bc * T_LEN;
    for (int p = tid; p < ext; p += THREADS) {
        int s = p - c0;
        sx[p] = (s >= 0 && s < T_LEN) ? xr[s] : 0.0f;
    }
    __syncthreads();

    const int lane = tid & 63;
    const int wid  = tid >> 6;

    #pragma unroll 1
    for (int k = 0; k < KPB; ++k) {
        const int kk = kg * KPB + k;

        // taps -> registers (compile-time indexed via unrolled j)
        float wj[NTAP];
        int   oj[NTAP];
        #pragma unroll
        for (int j = 0; j < NTAP; ++j) {
            wj[j] = tw[kk * NTAP + j];
            oj[j] = toff[kk * NTAP + j];
        }
        const float bk = bias[kk];

        float cnt = 0.0f;
        float mx  = -__builtin_inff();

        #pragma unroll
        for (int i = 0; i < 8; ++i) {
            const int t = tid + i * THREADS;
            if (t < T_LEN) {
                float y = bk;
                #pragma unroll
                for (int j = 0; j < NTAP; ++j)
                    y += wj[j] * sx[t + oj[j]];
                cnt += (y > 0.0f) ? 1.0f : 0.0f;
                mx   = fmaxf(mx, y);
            }
        }

        // 64-lane butterfly reduce
        #pragma unroll
        for (int m = 32; m >= 1; m >>= 1) {
            cnt += __shfl_xor(cnt, m, 64);
            mx   = fmaxf(mx, __shfl_xor(mx, m, 64));
        }
        if (lane == 0) {
            spart[wid][k][0] = cnt;
            spart[wid][k][1] = mx;
        }
    }
    __syncthreads();

    if (tid < KPB) {
        float cnt = spart[0][tid][0] + spart[1][tid][0]
                  + spart[2][tid][0] + spart[3][tid][0];
        float mx  = fmaxf(fmaxf(spart[0][tid][1], spart[1][tid][1]),
                          fmaxf(spart[2][tid][1], spart[3][tid][1]));
        const int kk = kg * KPB + tid;
        out[bc * (2 * NKER) + 2 * kk]     = cnt * (1.0f / T_LEN);
        out[bc * (2 * NKER) + 2 * kk + 1] = mx;
    }
}

extern "C" void kernel_launch(void* const* d_in, const int* in_sizes, int n_in,
                              void* d_out, int out_size, void* d_ws, size_t ws_size,
                              hipStream_t stream) {
    const float* x    = (const float*)d_in[0];
    const float* W    = (const float*)d_in[1];
    const float* bias = (const float*)d_in[2];
    float*       out  = (float*)d_out;

    const int Lmax = in_sizes[1] / NKER;

    float* tw   = (float*)d_ws;
    int*   toff = (int*)((char*)d_ws + NKER * NTAP * sizeof(float));

    rocket_prep<<<dim3(1), dim3(256), 0, stream>>>(W, Lmax, tw, toff);
    rocket_main<<<dim3(256, 8), dim3(THREADS), 0, stream>>>(x, bias, tw, toff, out, Lmax);
}

// Round 3
// 121.927 us; speedup vs baseline: 1.3469x; 1.3469x over previous
//
#include <hip/hip_runtime.h>

#define T_LEN   2000
#define NTAP    12      // max real taps is 11; pad with w=0,off=0
#define KPB     64      // kernels per block
#define NKER    256
#define NKG     (NKER / KPB)          // 4 kernel-groups
#define THREADS 256
#define EXT     2128                  // >= T_LEN + Lmax - 1 (Lmax<=127 -> 2126)
#define SX_BYTES ((EXT + EXT/8 + 2) * 16)

#define ONE2    0x3C003C00u   // {1,1} f16
#define C4096_2 0x6C006C00u   // {4096,4096} f16
#define NINF2   0xFC00FC00u   // {-inf,-inf} f16

// ---- packed-f16 ops via VOP3P asm (ROCm header lacks __hmax2 etc.) --------
__device__ inline unsigned pk_fma(unsigned a, unsigned b, unsigned c) {
    unsigned d; asm("v_pk_fma_f16 %0, %1, %2, %3" : "=v"(d) : "v"(a), "v"(b), "v"(c)); return d;
}
__device__ inline unsigned pk_add(unsigned a, unsigned b) {
    unsigned d; asm("v_pk_add_f16 %0, %1, %2" : "=v"(d) : "v"(a), "v"(b)); return d;
}
__device__ inline unsigned pk_mul(unsigned a, unsigned b) {
    unsigned d; asm("v_pk_mul_f16 %0, %1, %2" : "=v"(d) : "v"(a), "v"(b)); return d;
}
__device__ inline unsigned pk_max(unsigned a, unsigned b) {
    unsigned d; asm("v_pk_max_f16 %0, %1, %2" : "=v"(d) : "v"(a), "v"(b)); return d;
}
__device__ inline unsigned pk_min(unsigned a, unsigned b) {
    unsigned d; asm("v_pk_min_f16 %0, %1, %2" : "=v"(d) : "v"(a), "v"(b)); return d;
}
// strictly-positive indicator {0,1} per half: min(max(y*2^12*2^12, 0), 1)
// (min positive f16 subnormal 2^-24 -> exactly 1; y<=0 -> 0)
__device__ inline unsigned pk_ind(unsigned y) {
    return pk_min(pk_max(pk_mul(pk_mul(y, C4096_2), C4096_2), 0u), ONE2);
}
__device__ inline unsigned short f2h(float f) {
    return __builtin_bit_cast(unsigned short, (_Float16)f);
}
__device__ inline float h2f_lo(unsigned u) {
    return (float)__builtin_bit_cast(_Float16, (unsigned short)(u & 0xffffu));
}
__device__ inline float h2f_hi(unsigned u) {
    return (float)__builtin_bit_cast(_Float16, (unsigned short)(u >> 16));
}

// ---------------------------------------------------------------------------
// Prep: compress sparse bank into 12 (broadcast-f16-weight, offset) taps.
// ---------------------------------------------------------------------------
__global__ void rocket_prep(const float* __restrict__ W, int Lmax,
                            unsigned* __restrict__ tw2, int* __restrict__ toff) {
    int k = threadIdx.x;
    if (k >= NKER) return;
    int n = 0;
    for (int l = 0; l < Lmax; ++l) {
        float v = W[k * Lmax + l];
        if (v != 0.0f && n < NTAP) {
            unsigned h = f2h(v);
            tw2[k * NTAP + n]  = h | (h << 16);
            toff[k * NTAP + n] = l;
            ++n;
        }
    }
    for (; n < NTAP; ++n) { tw2[k * NTAP + n] = 0u; toff[k * NTAP + n] = 0; }
}

// ---------------------------------------------------------------------------
// Main: block = (bc, kernel-group of 64). LDS holds 8-wide shifted f16
// entries: entry p (16B) = f16{sx[p..p+7]} at byte ((p + p/8)<<4).
// Pad-every-8 makes the per-lane granule stride 9 (odd) -> 8 consecutive
// lanes cover all 32 banks once -> conflict-free ds_read_b128.
// Thread owns t = tid*8..tid*8+7. Per kernel: 12 x {b128 read + 4 pk_fma},
// packed cnt/max, 6-step butterfly, cross-wave combine.
// ---------------------------------------------------------------------------
__global__ __launch_bounds__(THREADS) void rocket_main(
    const float* __restrict__ x, const float* __restrict__ bias,
    const unsigned* __restrict__ tw2, const int* __restrict__ toff,
    float* __restrict__ out, int Lmax) {

    __shared__ __align__(16) unsigned char sx8[SX_BYTES];
    __shared__ unsigned spart[4][KPB][2];

    const int bc  = blockIdx.x;
    const int kg  = blockIdx.y;
    const int tid = threadIdx.x;
    const int c0  = (Lmax - 1) >> 1;
    const int ext = T_LEN + Lmax - 1;

    const float* __restrict__ xr = x + bc * T_LEN;

    // ---- build shifted f16 entries (9 consecutive entries per thread) ----
    {
        const int base = tid * 9;            // 256*9 = 2304 >= ext
        float xw[17];
        #pragma unroll
        for (int i = 0; i < 17; ++i) {
            int s = base + i - c0;
            xw[i] = (s >= 0 && s < T_LEN) ? xr[s] : 0.0f;
        }
        unsigned hh[17];
        #pragma unroll
        for (int i = 0; i < 17; ++i) hh[i] = f2h(xw[i]);
        #pragma unroll
        for (int i = 0; i < 9; ++i) {
            int p = base + i;
            if (p < ext) {
                int idx = p + (p >> 3);
                uint4 v;
                v.x = hh[i]     | (hh[i + 1] << 16);
                v.y = hh[i + 2] | (hh[i + 3] << 16);
                v.z = hh[i + 4] | (hh[i + 5] << 16);
                v.w = hh[i + 6] | (hh[i + 7] << 16);
                *reinterpret_cast<uint4*>(sx8 + ((unsigned)idx << 4)) = v;
            }
        }
    }
    __syncthreads();

    const int  lane   = tid & 63;
    const int  wid    = tid >> 6;
    const int  tb     = tid * 8;
    const bool is_act = (tb < T_LEN);

    #pragma unroll 1
    for (int k = 0; k < KPB; ++k) {
        const int kk = kg * KPB + k;

        unsigned wj[NTAP]; int oj[NTAP];
        #pragma unroll
        for (int j = 0; j < NTAP; ++j) {
            wj[j] = tw2[kk * NTAP + j];
            oj[j] = toff[kk * NTAP + j];
        }
        const float bk = bias[kk];

        unsigned cnt2 = 0u;
        unsigned m2   = NINF2;

        if (is_act) {
            unsigned hb = f2h(bk);
            unsigned b2 = hb | (hb << 16);
            unsigned ya = b2, yb = b2, yc = b2, yd = b2;
            #pragma unroll
            for (int j = 0; j < NTAP; ++j) {
                int p   = tb + oj[j];
                int idx = p + (p >> 3);
                uint4 v = *reinterpret_cast<const uint4*>(sx8 + ((unsigned)idx << 4));
                ya = pk_fma(wj[j], v.x, ya);
                yb = pk_fma(wj[j], v.y, yb);
                yc = pk_fma(wj[j], v.z, yc);
                yd = pk_fma(wj[j], v.w, yd);
            }
            cnt2 = pk_add(pk_add(pk_ind(ya), pk_ind(yb)),
                          pk_add(pk_ind(yc), pk_ind(yd)));
            m2 = pk_max(pk_max(ya, yb), pk_max(yc, yd));
        }

        // 6-step 64-lane butterfly on packed (cnt,max)
        #pragma unroll
        for (int m = 1; m < 64; m <<= 1) {
            unsigned oc = __shfl_xor(cnt2, m, 64);
            unsigned om = __shfl_xor(m2, m, 64);
            cnt2 = pk_add(cnt2, oc);
            m2   = pk_max(m2, om);
        }
        if (lane == 0) { spart[wid][k][0] = cnt2; spart[wid][k][1] = m2; }
    }
    __syncthreads();

    if (tid < KPB) {
        unsigned c2 = pk_add(pk_add(spart[0][tid][0], spart[1][tid][0]),
                             pk_add(spart[2][tid][0], spart[3][tid][0]));
        unsigned m2 = pk_max(pk_max(spart[0][tid][1], spart[1][tid][1]),
                             pk_max(spart[2][tid][1], spart[3][tid][1]));
        float cnt = h2f_lo(c2) + h2f_hi(c2);
        float mx  = fmaxf(h2f_lo(m2), h2f_hi(m2));
        const int kk = kg * KPB + tid;
        out[bc * (2 * NKER) + 2 * kk]     = cnt * (1.0f / T_LEN);
        out[bc * (2 * NKER) + 2 * kk + 1] = mx;
    }
}

extern "C" void kernel_launch(void* const* d_in, const int* in_sizes, int n_in,
                              void* d_out, int out_size, void* d_ws, size_t ws_size,
                              hipStream_t stream) {
    const float* x    = (const float*)d_in[0];
    const float* W    = (const float*)d_in[1];
    const float* bias = (const float*)d_in[2];
    float*       out  = (float*)d_out;

    const int Lmax = in_sizes[1] / NKER;

    unsigned* tw2  = (unsigned*)d_ws;
    int*      toff = (int*)((char*)d_ws + NKER * NTAP * sizeof(unsigned));

    rocket_prep<<<dim3(1), dim3(256), 0, stream>>>(W, Lmax, tw2, toff);
    rocket_main<<<dim3(256, NKG), dim3(THREADS), 0, stream>>>(x, bias, tw2, toff, out, Lmax);
}

// Round 4
// 88.087 us; speedup vs baseline: 1.8643x; 1.3842x over previous
//
#include <hip/hip_runtime.h>
#include <hip/hip_bf16.h>

#define T_LEN   2000
#define NKER    256
#define LPAD    128          // padded l-dim (Lmax <= 127, slot 127 = bias tap)
#define NE      2128         // shifted entries built (>= T_LEN + Lmax - 1)
#define THREADS 512
#define NTILES  125          // 2000 / 16

typedef int   v4i __attribute__((ext_vector_type(4)));
typedef float v4f __attribute__((ext_vector_type(4)));

// D = A*B + C with C = separate zero quad (no acc-init movs)
__device__ inline v4f mfma_z(v4i a, v4i b, v4f c) {
    v4f d;
    asm("v_mfma_f32_16x16x32_bf16 %0, %1, %2, %3" : "=v"(d) : "v"(a), "v"(b), "v"(c));
    return d;
}
__device__ inline void mfma_acc(v4f& acc, v4i a, v4i b) {
    asm("v_mfma_f32_16x16x32_bf16 %0, %1, %2, %0" : "+v"(acc) : "v"(a), "v"(b));
}
// chain-final MFMA: s_nop covers MFMA->VALU RAW hazard (opaque to compiler)
__device__ inline void mfma_acc_last(v4f& acc, v4i a, v4i b) {
    asm("v_mfma_f32_16x16x32_bf16 %0, %1, %2, %0\n\ts_nop 7"
        : "+v"(acc) : "v"(a), "v"(b));
}

__device__ inline unsigned short f2bf(float f) {
    return __builtin_bit_cast(unsigned short, __float2bfloat16(f));
}

// ---------------------------------------------------------------------------
// Prep: dense bf16 weight bank [256][128], zero-padded, bias in slot l=127.
// ---------------------------------------------------------------------------
__global__ void rocket_prep(const float* __restrict__ W,
                            const float* __restrict__ bias, int Lmax,
                            unsigned short* __restrict__ Wbf) {
    int k = threadIdx.x;
    if (k >= NKER) return;
    #pragma unroll 8
    for (int l = 0; l < LPAD; ++l) {
        float v = (l < Lmax) ? W[k * Lmax + l] : 0.0f;
        Wbf[k * LPAD + l] = f2bf(v);
    }
    Wbf[k * LPAD + 127] = f2bf(bias[k]);   // bias tap (l=127 always free)
}

// ---------------------------------------------------------------------------
// Main: 256 blocks (one bc each) x 512 threads (8 waves).
// Wave = (khalf h, t-quarter tq): 128 kernels (8 ktiles), ~31 t-tiles of 16.
// LDS: 8-wide shifted bf16 entries, entry p (16B) = bf16{sx[p..p+7]} at
// uint4-index p + p/8 (pad-every-8 -> uniform bank spread).
// Per t-tile: 4 ds_read_b128 (B-frags, shared by all 8 ktiles),
// 32 MFMA 16x16x32_bf16, cnt/max epilogue on 4 f32 acc per ktile.
// C layout (m89): row(kernel) = (lane>>4)*4 + reg, col(t) = lane&15.
// ---------------------------------------------------------------------------
__global__ __launch_bounds__(THREADS, 2) void rocket_main(
    const float* __restrict__ x, const unsigned short* __restrict__ Wbf,
    float* __restrict__ out, int Lmax) {

    __shared__ __align__(16) uint4 sx8[2400];     // idx max 2392
    __shared__ unsigned pc[NKER][4];
    __shared__ float    pm[NKER][4];

    const int bc  = blockIdx.x;
    const int tid = threadIdx.x;
    const int c0  = (Lmax - 1) >> 1;

    // ---- stage shifted entries: 5 consecutive entries per thread ----
    {
        const int base = tid * 5;
        if (base < NE) {
            float xv[12];
            #pragma unroll
            for (int i = 0; i < 12; ++i) {
                int s = base + i - c0;
                xv[i] = (s >= 0 && s < T_LEN) ? x[bc * T_LEN + s] : 0.0f;
            }
            unsigned hb[12];
            #pragma unroll
            for (int i = 0; i < 12; ++i) hb[i] = f2bf(xv[i]);
            #pragma unroll
            for (int i = 0; i < 5; ++i) {
                int p = base + i;
                if (p < NE) {
                    uint4 v;
                    v.x = hb[i]     | (hb[i + 1] << 16);
                    v.y = hb[i + 2] | (hb[i + 3] << 16);
                    v.z = hb[i + 4] | (hb[i + 5] << 16);
                    v.w = hb[i + 6] | (hb[i + 7] << 16);
                    sx8[p + (p >> 3)] = v;
                }
            }
        }
    }

    const int lane = tid & 63;
    const int wid  = tid >> 6;
    const int h    = wid & 1;        // kernel half
    const int tq   = wid >> 1;       // t quarter
    const int g    = lane >> 4;
    const int c    = lane & 15;

    // ---- A fragments: 8 ktiles x 4 k-steps, held in registers ----
    v4i afrag[8][4];
    #pragma unroll
    for (int kt = 0; kt < 8; ++kt) {
        #pragma unroll
        for (int s = 0; s < 4; ++s) {
            const unsigned short* src =
                Wbf + (h * 128 + kt * 16 + c) * LPAD + s * 32 + g * 8;
            afrag[kt][s] = *reinterpret_cast<const v4i*>(src);
        }
    }

    __syncthreads();

    unsigned cnt[8][4] = {};
    float    mx[8][4];
    #pragma unroll
    for (int kt = 0; kt < 8; ++kt)
        #pragma unroll
        for (int r = 0; r < 4; ++r) mx[kt][r] = -__builtin_inff();

    v4f zero4 = {0.f, 0.f, 0.f, 0.f};
    asm("" : "+v"(zero4));   // pin: keep zero quad materialized & hoisted

    const int pb   = g * 8 + c;                       // 0..39
    const unsigned voff = (unsigned)(pb + (pb >> 3)) << 4;
    const char* sxb = (const char*)sx8;

    const int tstart = (tq == 0) ? 0 : (1 + tq * 31); // 0,32,63,94
    const int tend   = tstart + ((tq == 0) ? 32 : 31);

    #pragma unroll 1
    for (int tile = tstart; tile < tend; ++tile) {
        const int t0 = tile << 4;
        v4i bfrag[4];
        #pragma unroll
        for (int s = 0; s < 4; ++s) {
            const int a = t0 + (s << 5);                   // mult of 8
            const unsigned abyte = (unsigned)(a + (a >> 3)) << 4;
            bfrag[s] = *reinterpret_cast<const v4i*>(sxb + abyte + voff);
        }
        // bias tap: element (g=3, j=7) of s=3 frag must be 1.0 (pairs with
        // Wbf[k][127] = bias). Patched early -> far from its MFMA use.
        if (g == 3) bfrag[3].w = (bfrag[3].w & 0xffff) | 0x3f800000;

        #pragma unroll
        for (int kt = 0; kt < 8; ++kt) {
            v4f acc = mfma_z(afrag[kt][0], bfrag[0], zero4);
            mfma_acc(acc, afrag[kt][1], bfrag[1]);
            mfma_acc(acc, afrag[kt][2], bfrag[2]);
            mfma_acc_last(acc, afrag[kt][3], bfrag[3]);
            #pragma unroll
            for (int r = 0; r < 4; ++r) {
                cnt[kt][r] += (acc[r] > 0.0f) ? 1u : 0u;
                mx[kt][r]  = fmaxf(mx[kt][r], acc[r]);
            }
        }
    }

    // ---- col reduce over 16 lanes via DPP row_ror (no LDS pipe) ----
    #pragma unroll
    for (int kt = 0; kt < 8; ++kt) {
        #pragma unroll
        for (int r = 0; r < 4; ++r) {
            unsigned cv = cnt[kt][r];
            cv += (unsigned)__builtin_amdgcn_update_dpp(0, (int)cv, 0x128, 0xF, 0xF, true);
            cv += (unsigned)__builtin_amdgcn_update_dpp(0, (int)cv, 0x124, 0xF, 0xF, true);
            cv += (unsigned)__builtin_amdgcn_update_dpp(0, (int)cv, 0x122, 0xF, 0xF, true);
            cv += (unsigned)__builtin_amdgcn_update_dpp(0, (int)cv, 0x121, 0xF, 0xF, true);
            float mv = mx[kt][r];
            mv = fmaxf(mv, __builtin_bit_cast(float,
                 __builtin_amdgcn_update_dpp(0, __builtin_bit_cast(int, mv), 0x128, 0xF, 0xF, true)));
            mv = fmaxf(mv, __builtin_bit_cast(float,
                 __builtin_amdgcn_update_dpp(0, __builtin_bit_cast(int, mv), 0x124, 0xF, 0xF, true)));
            mv = fmaxf(mv, __builtin_bit_cast(float,
                 __builtin_amdgcn_update_dpp(0, __builtin_bit_cast(int, mv), 0x122, 0xF, 0xF, true)));
            mv = fmaxf(mv, __builtin_bit_cast(float,
                 __builtin_amdgcn_update_dpp(0, __builtin_bit_cast(int, mv), 0x121, 0xF, 0xF, true)));
            if (c == 0) {
                const int kk = h * 128 + kt * 16 + g * 4 + r;
                pc[kk][tq] = cv;
                pm[kk][tq] = mv;
            }
        }
    }
    __syncthreads();

    if (tid < NKER) {
        unsigned ct = pc[tid][0] + pc[tid][1] + pc[tid][2] + pc[tid][3];
        float mv = fmaxf(fmaxf(pm[tid][0], pm[tid][1]),
                         fmaxf(pm[tid][2], pm[tid][3]));
        out[bc * (2 * NKER) + 2 * tid]     = (float)ct * (1.0f / T_LEN);
        out[bc * (2 * NKER) + 2 * tid + 1] = mv;
    }
}

extern "C" void kernel_launch(void* const* d_in, const int* in_sizes, int n_in,
                              void* d_out, int out_size, void* d_ws, size_t ws_size,
                              hipStream_t stream) {
    const float* x    = (const float*)d_in[0];
    const float* W    = (const float*)d_in[1];
    const float* bias = (const float*)d_in[2];
    float*       out  = (float*)d_out;

    const int Lmax = in_sizes[1] / NKER;

    unsigned short* Wbf = (unsigned short*)d_ws;   // 256*128*2 = 64 KB

    rocket_prep<<<dim3(1), dim3(256), 0, stream>>>(W, bias, Lmax, Wbf);
    rocket_main<<<dim3(256), dim3(THREADS), 0, stream>>>(x, Wbf, out, Lmax);
}

// Round 5
// 51.161 us; speedup vs baseline: 3.2099x; 1.7218x over previous
//
#include <hip/hip_runtime.h>
#include <hip/hip_bf16.h>

#define T_LEN   2000
#define NKER    256
#define LPAD    128          // padded l-dim (Lmax <= 127, slot 127 = bias tap)
#define NE      2128         // shifted entries built (>= T_LEN + Lmax - 1)
#define THREADS 512

typedef int   v4i   __attribute__((ext_vector_type(4)));
typedef float v4f   __attribute__((ext_vector_type(4)));
typedef short bf16x8 __attribute__((ext_vector_type(8)));

__device__ inline unsigned f2bf(float f) {
    return (unsigned)__builtin_bit_cast(unsigned short, __float2bfloat16(f));
}

// ---------------------------------------------------------------------------
// Prep: dense bf16 weight bank [256][128], zero-padded, bias in slot l=127.
// 256 blocks (one kernel each) x 64 threads; thread handles l=2t,2t+1 and
// writes one dword (coalesced).
// ---------------------------------------------------------------------------
__global__ void rocket_prep(const float* __restrict__ W,
                            const float* __restrict__ bias, int Lmax,
                            unsigned* __restrict__ Wbf32) {
    const int k = blockIdx.x;
    const int t = threadIdx.x;           // 0..63
    const int l0 = 2 * t, l1 = 2 * t + 1;
    float v0 = (l0 < Lmax) ? W[k * Lmax + l0] : 0.0f;
    float v1 = (l1 < Lmax) ? W[k * Lmax + l1] : 0.0f;
    if (l1 == LPAD - 1) v1 = bias[k];    // bias tap (slot 127 always free)
    Wbf32[k * (LPAD / 2) + t] = f2bf(v0) | (f2bf(v1) << 16);
}

// ---------------------------------------------------------------------------
// Main: 256 blocks (one bc each) x 512 threads (8 waves).
// Wave = (khalf h, t-quarter tq): 128 kernels (8 ktiles), ~31 t-tiles of 16.
// LDS: 8-wide shifted bf16 entries, entry p (16B) = bf16{sx[p..p+7]} at
// uint4-index p + p/8 (pad-every-8 -> uniform bank spread).
// Per t-tile: 4 ds_read_b128 (B-frags, shared by all 8 ktiles),
// 32 MFMA 16x16x32_bf16 (builtin -> compiler schedules hazards/interleave),
// cnt/max epilogue on 4 f32 acc per ktile.
// C layout (m89): row(kernel) = (lane>>4)*4 + reg, col(t) = lane&15.
// ---------------------------------------------------------------------------
__global__ __launch_bounds__(THREADS, 2) void rocket_main(
    const float* __restrict__ x, const unsigned short* __restrict__ Wbf,
    float* __restrict__ out, int Lmax) {

    __shared__ __align__(16) uint4 sx8[2400];     // idx max 2392
    __shared__ unsigned pc[NKER][4];
    __shared__ float    pm[NKER][4];

    const int bc  = blockIdx.x;
    const int tid = threadIdx.x;
    const int c0  = (Lmax - 1) >> 1;

    // ---- stage shifted entries: 5 consecutive entries per thread ----
    {
        const int base = tid * 5;
        if (base < NE) {
            float xv[12];
            #pragma unroll
            for (int i = 0; i < 12; ++i) {
                int s = base + i - c0;
                xv[i] = (s >= 0 && s < T_LEN) ? x[bc * T_LEN + s] : 0.0f;
            }
            unsigned hb[12];
            #pragma unroll
            for (int i = 0; i < 12; ++i) hb[i] = f2bf(xv[i]);
            #pragma unroll
            for (int i = 0; i < 5; ++i) {
                int p = base + i;
                if (p < NE) {
                    uint4 v;
                    v.x = hb[i]     | (hb[i + 1] << 16);
                    v.y = hb[i + 2] | (hb[i + 3] << 16);
                    v.z = hb[i + 4] | (hb[i + 5] << 16);
                    v.w = hb[i + 6] | (hb[i + 7] << 16);
                    sx8[p + (p >> 3)] = v;
                }
            }
        }
    }

    const int lane = tid & 63;
    const int wid  = tid >> 6;
    const int h    = wid & 1;        // kernel half
    const int tq   = wid >> 1;       // t quarter
    const int g    = lane >> 4;
    const int c    = lane & 15;

    // ---- A fragments: 8 ktiles x 4 k-steps, held in registers ----
    bf16x8 afrag[8][4];
    #pragma unroll
    for (int kt = 0; kt < 8; ++kt) {
        #pragma unroll
        for (int s = 0; s < 4; ++s) {
            const unsigned short* src =
                Wbf + (h * 128 + kt * 16 + c) * LPAD + s * 32 + g * 8;
            afrag[kt][s] = *reinterpret_cast<const bf16x8*>(src);
        }
    }

    __syncthreads();

    unsigned cnt[8][4] = {};
    float    mx[8][4];
    #pragma unroll
    for (int kt = 0; kt < 8; ++kt)
        #pragma unroll
        for (int r = 0; r < 4; ++r) mx[kt][r] = -__builtin_inff();

    const int pb = g * 8 + c;                        // 0..39
    const unsigned voff = (unsigned)(pb + (pb >> 3)) << 4;
    const char* sxb = (const char*)sx8;

    const int tstart = (tq == 0) ? 0 : (1 + tq * 31); // 0,32,63,94
    const int tend   = tstart + ((tq == 0) ? 32 : 31);

    #pragma unroll 1
    for (int tile = tstart; tile < tend; ++tile) {
        const int t0 = tile << 4;
        uint4 braw[4];
        #pragma unroll
        for (int s = 0; s < 4; ++s) {
            const int a = t0 + (s << 5);                   // mult of 8
            const unsigned abyte = (unsigned)(a + (a >> 3)) << 4;
            braw[s] = *reinterpret_cast<const uint4*>(sxb + abyte + voff);
        }
        // bias tap: element (g=3, j=7) of s=3 frag must be 1.0 (pairs with
        // Wbf[k][127] = bias).
        if (g == 3) braw[3].w = (braw[3].w & 0xffff) | 0x3f800000;

        bf16x8 bfrag[4];
        #pragma unroll
        for (int s = 0; s < 4; ++s) bfrag[s] = __builtin_bit_cast(bf16x8, braw[s]);

        #pragma unroll
        for (int kt = 0; kt < 8; ++kt) {
            v4f acc = {0.f, 0.f, 0.f, 0.f};
            acc = __builtin_amdgcn_mfma_f32_16x16x32_bf16(afrag[kt][0], bfrag[0], acc, 0, 0, 0);
            acc = __builtin_amdgcn_mfma_f32_16x16x32_bf16(afrag[kt][1], bfrag[1], acc, 0, 0, 0);
            acc = __builtin_amdgcn_mfma_f32_16x16x32_bf16(afrag[kt][2], bfrag[2], acc, 0, 0, 0);
            acc = __builtin_amdgcn_mfma_f32_16x16x32_bf16(afrag[kt][3], bfrag[3], acc, 0, 0, 0);
            #pragma unroll
            for (int r = 0; r < 4; ++r) {
                cnt[kt][r] += (acc[r] > 0.0f) ? 1u : 0u;
                mx[kt][r]  = fmaxf(mx[kt][r], acc[r]);
            }
        }
    }

    // ---- col reduce over 16 lanes via DPP row_ror (no LDS pipe) ----
    #pragma unroll
    for (int kt = 0; kt < 8; ++kt) {
        #pragma unroll
        for (int r = 0; r < 4; ++r) {
            unsigned cv = cnt[kt][r];
            cv += (unsigned)__builtin_amdgcn_update_dpp(0, (int)cv, 0x128, 0xF, 0xF, true);
            cv += (unsigned)__builtin_amdgcn_update_dpp(0, (int)cv, 0x124, 0xF, 0xF, true);
            cv += (unsigned)__builtin_amdgcn_update_dpp(0, (int)cv, 0x122, 0xF, 0xF, true);
            cv += (unsigned)__builtin_amdgcn_update_dpp(0, (int)cv, 0x121, 0xF, 0xF, true);
            float mv = mx[kt][r];
            mv = fmaxf(mv, __builtin_bit_cast(float,
                 __builtin_amdgcn_update_dpp(0, __builtin_bit_cast(int, mv), 0x128, 0xF, 0xF, true)));
            mv = fmaxf(mv, __builtin_bit_cast(float,
                 __builtin_amdgcn_update_dpp(0, __builtin_bit_cast(int, mv), 0x124, 0xF, 0xF, true)));
            mv = fmaxf(mv, __builtin_bit_cast(float,
                 __builtin_amdgcn_update_dpp(0, __builtin_bit_cast(int, mv), 0x122, 0xF, 0xF, true)));
            mv = fmaxf(mv, __builtin_bit_cast(float,
                 __builtin_amdgcn_update_dpp(0, __builtin_bit_cast(int, mv), 0x121, 0xF, 0xF, true)));
            if (c == 0) {
                const int kk = h * 128 + kt * 16 + g * 4 + r;
                pc[kk][tq] = cv;
                pm[kk][tq] = mv;
            }
        }
    }
    __syncthreads();

    if (tid < NKER) {
        unsigned ct = pc[tid][0] + pc[tid][1] + pc[tid][2] + pc[tid][3];
        float mv = fmaxf(fmaxf(pm[tid][0], pm[tid][1]),
                         fmaxf(pm[tid][2], pm[tid][3]));
        out[bc * (2 * NKER) + 2 * tid]     = (float)ct * (1.0f / T_LEN);
        out[bc * (2 * NKER) + 2 * tid + 1] = mv;
    }
}

extern "C" void kernel_launch(void* const* d_in, const int* in_sizes, int n_in,
                              void* d_out, int out_size, void* d_ws, size_t ws_size,
                              hipStream_t stream) {
    const float* x    = (const float*)d_in[0];
    const float* W    = (const float*)d_in[1];
    const float* bias = (const float*)d_in[2];
    float*       out  = (float*)d_out;

    const int Lmax = in_sizes[1] / NKER;

    unsigned* Wbf32 = (unsigned*)d_ws;             // 256*128*2 = 64 KB

    rocket_prep<<<dim3(NKER), dim3(64), 0, stream>>>(W, bias, Lmax, Wbf32);
    rocket_main<<<dim3(256), dim3(THREADS), 0, stream>>>(
        x, (const unsigned short*)Wbf32, out, Lmax);
}